// Round 11
// baseline (92.212 us; speedup 1.0000x reference)
//
#include <hip/hip_runtime.h>
#include <math.h>

// Problem constants (from the reference):
//  levels: (64,64,s=8,bs=32) (32,32,s=16,bs=64) (16,16,s=32,bs=128) (8,8,s=64,bs=256)
//  K = 9 anchors/position (3 ratios x 3 scales), A = 48960, B = 16, M = 64 GT boxes
// Level boundaries 36864/46080/48384 are 64-aligned -> every wave is single-
// level and covers a contiguous hw range -> analytic conservative window.
// History: R5 prep+LDS-walk 91.3; R6 batch-amortize regressed (killed TLP +
// 4x serial walk); R7 readlane walk +6.5us (extra VALU/trip); R8 fused
// single-launch analytic-window = 88.8 (best); R9 dual-chain ILP neutral;
// R10 drop in-loop sarea read neutral. Walk is NOT the binding constraint.
// R11: isolate the per-block term - 1024-thread blocks, 4x fewer dispatches/
// stagings/barriers/f64-table builds; per-thread work byte-identical.
#define A_TOTAL 48960
#define M_GT    64
#define B_BATCH 16
#define BLK     1024

__global__ __launch_bounds__(BLK) void anchors_assign_kernel(
    const float* __restrict__ gt_boxes,   // (B, 64, 4) xyxy
    const int*   __restrict__ gt_labels,  // (B, 64)
    float* __restrict__ out_loc,          // (B, A, 4)
    float* __restrict__ out_cls)          // (B, A)
{
    __shared__ float4 sbox[M_GT];
    __shared__ float  slab[M_GT];
    __shared__ float2 swh[36];            // (aw, ah) per lvl*9+k, f64-exact cast

    const int b    = blockIdx.y;
    const int tid  = threadIdx.x;
    const int lane = tid & 63;

    if (tid < M_GT) {
        // Stage this batch's GT boxes (64 x float4 = 1 KiB)
        const float4 g = ((const float4*)gt_boxes)[b * M_GT + tid];
        sbox[tid] = g;
        slab[tid] = (float)gt_labels[b * M_GT + tid];
    } else if (tid < M_GT + 36) {
        // Build the 36-entry anchor-wh table, bit-exact vs numpy:
        // a = bs*scale; area = a*a; w = sqrt(area*rr); h = w/rr; cast f32.
        const int t   = tid - M_GT;        // 0..35
        const int lvl = t / 9, k = t - lvl * 9;
        const int r   = k / 3, s = k - r * 3;
        const double sc = (s == 0) ? 1.0 : ((s == 1) ? 1.2599210498948732   // 2^(1/3)
                                                     : 1.5874010519681994); // 2^(2/3)
        const double rr = (r == 0) ? 0.5 : ((r == 1) ? 1.0 : 2.0);
        const double bs   = (double)(32 << lvl);
        const double av   = bs * sc;
        const double area = av * av;
        const double wd   = sqrt(area * rr);
        swh[t] = make_float2((float)wd, (float)(wd / rr));
    }
    __syncthreads();

    const int a = blockIdx.x * BLK + tid;
    if (a >= A_TOTAL) return;   // tail exits in whole waves, after the barrier

    // ---- decode anchor index (shifts + magic-div by 9) ----
    int local, lgW, lvl;
    if (a < 36864)      { local = a;         lgW = 6; lvl = 0; }
    else if (a < 46080) { local = a - 36864; lgW = 5; lvl = 1; }
    else if (a < 48384) { local = a - 46080; lgW = 4; lvl = 2; }
    else                { local = a - 48384; lgW = 3; lvl = 3; }
    const float stride_f = (float)(8 << lvl);

    const int hw = local / 9;
    const int k  = local - hw * 9;
    const int y  = hw >> lgW;
    const int x  = hw & ((1 << lgW) - 1);

    const float2 wh = swh[lvl * 9 + k];    // 9 distinct addrs/wave -> ~no conflict
    const float aw = wh.x, ah = wh.y;
    const float acx = ((float)x + 0.5f) * stride_f;   // exact, same form as ref
    const float acy = ((float)y + 0.5f) * stride_f;
    const float hx = aw * 0.5f, hy = ah * 0.5f;
    const float ax1 = acx - hx, ay1 = acy - hy;
    const float ax2 = acx + hx, ay2 = acy + hy;
    const float areaA = (ax2 - ax1) * (ay2 - ay1);    // ref recomputes from xyxy

    // ---- analytic conservative wave window (wave-uniform values) ----
    // Conservative ⊇ exact union is safe: pruned boxes have inter==0 with
    // every anchor in the wave; 0-iou can't win under strict '>' with the
    // b_inter=0 init (all-pruned -> bidx=0 = np.argmax of all-zero row).
    const int l0  = local - lane;
    const int hw0 = l0 / 9;
    const int hw1 = (l0 + 63) / 9;
    const int y0  = hw0 >> lgW, y1 = hw1 >> lgW;
    int x0, x1;
    if (y0 == y1) { x0 = hw0 & ((1 << lgW) - 1); x1 = hw1 & ((1 << lgW) - 1); }
    else          { x0 = 0;                      x1 = (1 << lgW) - 1;         }
    const float margin = (float)(32 << lvl) * 1.1225f;  // >= bs*2^(2/3)*sqrt(.5)
    const float wx1 = ((float)x0 + 0.5f) * stride_f - margin;
    const float wx2 = ((float)x1 + 0.5f) * stride_f + margin;
    const float wy1 = ((float)y0 + 0.5f) * stride_f - margin;
    const float wy2 = ((float)y1 + 0.5f) * stride_f + margin;

    // ---- candidate mask: lane j tests GT box j against the wave window ----
    const float4 gb = sbox[lane];
    const bool cand = (fminf(wx2, gb.z) > fmaxf(wx1, gb.x)) &&
                      (fminf(wy2, gb.w) > fmaxf(wy1, gb.y));
    unsigned long long mask = __ballot(cand);   // wave-uniform

    // ---- division-free IoU argmax over candidates, ascending j ----
    // iou_j > iou_best <=> inter_j*den_best > inter_best*den_j (dens > 0);
    // strict '>' keeps the first max, matching np.argmax. Uniform j -> LDS
    // broadcast; area_g recomputed from the b128 data, bit-identical fp32.
    float b_inter = 0.0f, b_den = 1.0f;
    int   bidx = 0;
    while (mask) {
        const int j = (int)__builtin_ctzll(mask);
        mask &= mask - 1;
        const float4 g = sbox[j];
        const float ga = (g.z - g.x) * (g.w - g.y);       // == ref's area_g bits
        const float ltx = fmaxf(ax1, g.x), lty = fmaxf(ay1, g.y);
        const float rbx = fminf(ax2, g.z), rby = fminf(ay2, g.w);
        const float wx = fmaxf(rbx - ltx, 0.0f);
        const float wy = fmaxf(rby - lty, 0.0f);
        const float inter = wx * wy;
        const float den   = (areaA + ga) - inter;         // same assoc as ref
        if (inter * b_den > b_inter * den) {
            b_inter = inter; b_den = den; bidx = j;
        }
    }
    const float best = b_inter / b_den;   // exact IEEE: bit-matches ref's iou

    // ---- label thresholding (order matches ref: ign first, bg overrides) ----
    float lab = slab[bidx];
    if (best > 0.4f && best < 0.5f) lab = -1.0f;
    if (best < 0.4f)                lab = 0.0f;

    // ---- box deltas (v_rcp muls; loc-only error ~1e-6 << tol 3.92) ----
    const float4 g = sbox[bidx];
    const float rcw = __builtin_amdgcn_rcpf(aw);
    const float rch = __builtin_amdgcn_rcpf(ah);
    const float gcx = (g.x + g.z) * 0.5f;
    const float gcy = (g.y + g.w) * 0.5f;
    const float tx = (gcx - acx) * rcw * 10.0f;        // /(aw*0.1)
    const float ty = (gcy - acy) * rch * 10.0f;
    const float tw = __logf((g.z - g.x) * rcw) * 5.0f; // /0.2
    const float th = __logf((g.w - g.y) * rch) * 5.0f;

    const size_t idx = (size_t)b * A_TOTAL + a;
    ((float4*)out_loc)[idx] = make_float4(tx, ty, tw, th);  // coalesced 16B store
    out_cls[idx] = lab;
}

extern "C" void kernel_launch(void* const* d_in, const int* in_sizes, int n_in,
                              void* d_out, int out_size, void* d_ws, size_t ws_size,
                              hipStream_t stream) {
    // inputs: f3..f6 (data unused; shapes compile-time), gt_boxes f32, gt_labels int
    const float* gt_boxes  = (const float*)d_in[4];
    const int*   gt_labels = (const int*)d_in[5];

    float* out_loc = (float*)d_out;                                  // (B, A, 4)
    float* out_cls = (float*)d_out + (size_t)B_BATCH * A_TOTAL * 4;  // (B, A)

    dim3 grid((A_TOTAL + BLK - 1) / BLK, B_BATCH);   // 48 x 16 = 768 blocks
    anchors_assign_kernel<<<grid, BLK, 0, stream>>>(gt_boxes, gt_labels,
                                                    out_loc, out_cls);
}

// Round 12
// 88.558 us; speedup vs baseline: 1.0413x; 1.0413x over previous
//
#include <hip/hip_runtime.h>
#include <math.h>

// Problem constants (from the reference):
//  levels: (64,64,s=8,bs=32) (32,32,s=16,bs=64) (16,16,s=32,bs=128) (8,8,s=64,bs=256)
//  K = 9 anchors/position (3 ratios x 3 scales), A = 48960, B = 16, M = 64 GT boxes
// Level boundaries 36864/46080/48384 are 64-aligned -> every wave is single-
// level and covers a contiguous hw range -> analytic conservative window.
// History: R5 prep+LDS-walk 91.3; R6 batch-amortize regressed (killed TLP);
// R7 readlane walk +6.5us; R8 fused single-launch analytic-window = 88.8
// (BEST); R9 dual-chain ILP neutral; R10 sarea-recompute neutral; R11
// 1024-thread blocks +3.4us (load-balance loss > per-block saving).
// R12: revert to R8 exactly - the empirical optimum. Remaining dur is
// ~68us harness fills/restores at the HBM roofline + ~21us kernel that
// resisted four orthogonal counter-motivated attacks.
#define A_TOTAL 48960
#define M_GT    64
#define B_BATCH 16

__global__ __launch_bounds__(256) void anchors_assign_kernel(
    const float* __restrict__ gt_boxes,   // (B, 64, 4) xyxy
    const int*   __restrict__ gt_labels,  // (B, 64)
    float* __restrict__ out_loc,          // (B, A, 4)
    float* __restrict__ out_cls)          // (B, A)
{
    __shared__ float4 sbox[M_GT];
    __shared__ float  sarea[M_GT];
    __shared__ float  slab[M_GT];
    __shared__ float2 swh[36];            // (aw, ah) per lvl*9+k, f64-exact cast

    const int b    = blockIdx.y;
    const int tid  = threadIdx.x;
    const int lane = tid & 63;

    if (tid < M_GT) {
        // Stage this batch's GT boxes (64 x float4 = 1 KiB)
        const float4 g = ((const float4*)gt_boxes)[b * M_GT + tid];
        sbox[tid]  = g;
        sarea[tid] = (g.z - g.x) * (g.w - g.y);   // same op order as ref
        slab[tid]  = (float)gt_labels[b * M_GT + tid];
    } else if (tid < M_GT + 36) {
        // Spare threads build the 36-entry anchor-wh table, bit-exact vs numpy:
        // a = bs*scale; area = a*a; w = sqrt(area*rr); h = w/rr; cast f32.
        // Cost hidden behind the staging barrier.
        const int t   = tid - M_GT;        // 0..35
        const int lvl = t / 9, k = t - lvl * 9;
        const int r   = k / 3, s = k - r * 3;
        const double sc = (s == 0) ? 1.0 : ((s == 1) ? 1.2599210498948732   // 2^(1/3)
                                                     : 1.5874010519681994); // 2^(2/3)
        const double rr = (r == 0) ? 0.5 : ((r == 1) ? 1.0 : 2.0);
        const double bs   = (double)(32 << lvl);
        const double av   = bs * sc;
        const double area = av * av;
        const double wd   = sqrt(area * rr);
        swh[t] = make_float2((float)wd, (float)(wd / rr));
    }
    __syncthreads();

    const int a = blockIdx.x * 256 + tid;
    if (a >= A_TOTAL) return;   // tail is whole waves, after the barrier

    // ---- decode anchor index (shifts + magic-div by 9) ----
    int local, lgW, lvl;
    if (a < 36864)      { local = a;         lgW = 6; lvl = 0; }
    else if (a < 46080) { local = a - 36864; lgW = 5; lvl = 1; }
    else if (a < 48384) { local = a - 46080; lgW = 4; lvl = 2; }
    else                { local = a - 48384; lgW = 3; lvl = 3; }
    const float stride_f = (float)(8 << lvl);

    const int hw = local / 9;
    const int k  = local - hw * 9;
    const int y  = hw >> lgW;
    const int x  = hw & ((1 << lgW) - 1);

    const float2 wh = swh[lvl * 9 + k];    // 9 distinct addrs/wave -> ~no conflict
    const float aw = wh.x, ah = wh.y;
    const float acx = ((float)x + 0.5f) * stride_f;   // exact, same form as ref
    const float acy = ((float)y + 0.5f) * stride_f;
    const float hx = aw * 0.5f, hy = ah * 0.5f;
    const float ax1 = acx - hx, ay1 = acy - hy;
    const float ax2 = acx + hx, ay2 = acy + hy;
    const float areaA = (ax2 - ax1) * (ay2 - ay1);    // ref recomputes from xyxy

    // ---- analytic conservative wave window (wave-uniform values) ----
    // Conservative ⊇ exact union is safe: pruned boxes have inter==0 with
    // every anchor in the wave; 0-iou can't win under strict '>' with the
    // b_inter=0 init (all-pruned -> bidx=0 = np.argmax of all-zero row).
    const int l0  = local - lane;
    const int hw0 = l0 / 9;
    const int hw1 = (l0 + 63) / 9;
    const int y0  = hw0 >> lgW, y1 = hw1 >> lgW;
    int x0, x1;
    if (y0 == y1) { x0 = hw0 & ((1 << lgW) - 1); x1 = hw1 & ((1 << lgW) - 1); }
    else          { x0 = 0;                      x1 = (1 << lgW) - 1;         }
    const float margin = (float)(32 << lvl) * 1.1225f;  // >= bs*2^(2/3)*sqrt(.5)
    const float wx1 = ((float)x0 + 0.5f) * stride_f - margin;
    const float wx2 = ((float)x1 + 0.5f) * stride_f + margin;
    const float wy1 = ((float)y0 + 0.5f) * stride_f - margin;
    const float wy2 = ((float)y1 + 0.5f) * stride_f + margin;

    // ---- candidate mask: lane j tests GT box j against the wave window ----
    const float4 gb = sbox[lane];
    const bool cand = (fminf(wx2, gb.z) > fmaxf(wx1, gb.x)) &&
                      (fminf(wy2, gb.w) > fmaxf(wy1, gb.y));
    unsigned long long mask = __ballot(cand);   // wave-uniform

    // ---- division-free IoU argmax over candidates, ascending j ----
    // iou_j > iou_best <=> inter_j*den_best > inter_best*den_j (dens > 0);
    // strict '>' keeps the first max, matching np.argmax. Uniform j -> LDS
    // broadcast; latency hidden by 12 waves/SIMD TLP (R6/R7 lessons).
    float b_inter = 0.0f, b_den = 1.0f;
    int   bidx = 0;
    while (mask) {
        const int j = (int)__builtin_ctzll(mask);
        mask &= mask - 1;
        const float4 g = sbox[j];
        const float ltx = fmaxf(ax1, g.x), lty = fmaxf(ay1, g.y);
        const float rbx = fminf(ax2, g.z), rby = fminf(ay2, g.w);
        const float wx = fmaxf(rbx - ltx, 0.0f);
        const float wy = fmaxf(rby - lty, 0.0f);
        const float inter = wx * wy;
        const float den   = (areaA + sarea[j]) - inter;   // same assoc as ref
        if (inter * b_den > b_inter * den) {
            b_inter = inter; b_den = den; bidx = j;
        }
    }
    const float best = b_inter / b_den;   // exact IEEE: bit-matches ref's iou

    // ---- label thresholding (order matches ref: ign first, bg overrides) ----
    float lab = slab[bidx];
    if (best > 0.4f && best < 0.5f) lab = -1.0f;
    if (best < 0.4f)                lab = 0.0f;

    // ---- box deltas (v_rcp muls; loc-only error ~1e-6 << tol 3.92) ----
    const float4 g = sbox[bidx];
    const float rcw = __builtin_amdgcn_rcpf(aw);
    const float rch = __builtin_amdgcn_rcpf(ah);
    const float gcx = (g.x + g.z) * 0.5f;
    const float gcy = (g.y + g.w) * 0.5f;
    const float tx = (gcx - acx) * rcw * 10.0f;        // /(aw*0.1)
    const float ty = (gcy - acy) * rch * 10.0f;
    const float tw = __logf((g.z - g.x) * rcw) * 5.0f; // /0.2
    const float th = __logf((g.w - g.y) * rch) * 5.0f;

    const size_t idx = (size_t)b * A_TOTAL + a;
    ((float4*)out_loc)[idx] = make_float4(tx, ty, tw, th);  // coalesced 16B store
    out_cls[idx] = lab;
}

extern "C" void kernel_launch(void* const* d_in, const int* in_sizes, int n_in,
                              void* d_out, int out_size, void* d_ws, size_t ws_size,
                              hipStream_t stream) {
    // inputs: f3..f6 (data unused; shapes compile-time), gt_boxes f32, gt_labels int
    const float* gt_boxes  = (const float*)d_in[4];
    const int*   gt_labels = (const int*)d_in[5];

    float* out_loc = (float*)d_out;                                  // (B, A, 4)
    float* out_cls = (float*)d_out + (size_t)B_BATCH * A_TOTAL * 4;  // (B, A)

    dim3 grid((A_TOTAL + 255) / 256, B_BATCH);   // 192 x 16 blocks, single launch
    anchors_assign_kernel<<<grid, 256, 0, stream>>>(gt_boxes, gt_labels,
                                                    out_loc, out_cls);
}